// Round 5
// baseline (283.711 us; speedup 1.0000x reference)
//
#include <hip/hip_runtime.h>

#define EPS 1e-5f

// Problem dims (fixed by setup_inputs)
constexpr int T  = 512;
constexpr int B  = 64;
constexpr int HU = 1024;
constexpr int S  = 1024;
constexpr int C  = B * HU;       // 65536 (b,hu) columns
constexpr int TSPLIT = 32;       // T-chunks for the fused pass (16 t's each)

// ws layout (in floats); high-water ~8.5 MB
constexpr size_t OFF_SIW0 = 0;            // [64][10]
constexpr size_t OFF_W    = 1024;         // [512]   e^{s_tau} for tau<512 (t<8)
constexpr size_t OFF_ESC  = 2048;         // [32768] e^{s} for ALL (t,b) -> Z
constexpr size_t OFF_PART = 35840;        // [32][65536] partial weighted sums

// ---------------------------------------------------------------------------
// Shared device helper: MLP head  (10 -> 5 -> 1), returns score.
// ---------------------------------------------------------------------------
__device__ __forceinline__ float mlp_head(
    const float* __restrict__ u10,
    const float* __restrict__ b0, const float* __restrict__ g0,
    const float* __restrict__ be0,const float* __restrict__ m0,
    const float* __restrict__ v0,
    const float* __restrict__ W1, const float* __restrict__ b1,
    const float* __restrict__ g1, const float* __restrict__ be1,
    const float* __restrict__ m1, const float* __restrict__ v1,
    const float* __restrict__ W2, const float* __restrict__ b2) {
    float y[10];
#pragma unroll
    for (int j = 0; j < 10; ++j) {
        float u = (u10[j] + b0[j] - m0[j]) * (1.0f / sqrtf(v0[j] + EPS)) * g0[j]
                  + be0[j];
        y[j] = fmaxf(u, 0.f);
    }
    float z[5];
#pragma unroll
    for (int i = 0; i < 5; ++i) {
        float u = b1[i];
#pragma unroll
        for (int j = 0; j < 10; ++j) u = fmaf(y[j], W1[j * 5 + i], u);
        u = (u - m1[i]) * (1.0f / sqrtf(v1[i] + EPS)) * g1[i] + be1[i];
        z[i] = fmaxf(u, 0.f);
    }
    float sc = b2[0];
#pragma unroll
    for (int i = 0; i < 5; ++i) sc = fmaf(z[i], W2[i], sc);
    return sc;
}

// ---------------------------------------------------------------------------
// kA: the 512 USED weights w[tau] = e^{s(t,b)}, tau = t*64+b, t<8.
// Block e = (t<8, cb): reads h[t,cb,:] (4KB) + si[cb,:] (4KB), computes the
// full score in-block. Blocks with t==0 also export siW0[cb][10] for kB heads.
// ---------------------------------------------------------------------------
__global__ __launch_bounds__(256) void k_weights(
    const float* __restrict__ h,  const float* __restrict__ si,
    const float* __restrict__ W0,
    const float* __restrict__ b0, const float* __restrict__ g0,
    const float* __restrict__ be0,const float* __restrict__ m0,
    const float* __restrict__ v0,
    const float* __restrict__ W1, const float* __restrict__ b1,
    const float* __restrict__ g1, const float* __restrict__ be1,
    const float* __restrict__ m1, const float* __restrict__ v1,
    const float* __restrict__ W2, const float* __restrict__ b2,
    float* __restrict__ w, float* __restrict__ siW0out) {
    const int e   = blockIdx.x;
    const int t   = e >> 6;              // 0..7
    const int cb  = e & 63;              // b
    const int tid = threadIdx.x;
    const int wv  = tid >> 6, ln = tid & 63;

    const float4 hv = *(const float4*)(h  + (size_t)t  * C + (size_t)cb * HU + tid * 4);
    const float4 sv = *(const float4*)(si + (size_t)cb * S + tid * 4);
    const float* wsb = W0 + (size_t)(4 * tid) * 10;          // si half rows
    const float* whb = W0 + (size_t)(1024 + 4 * tid) * 10;   // h half rows

    float ssi[10], shh[10];
#pragma unroll
    for (int j = 0; j < 10; ++j) { ssi[j] = 0.f; shh[j] = 0.f; }
#pragma unroll
    for (int d = 0; d < 4; ++d) {
        const float sx = (&sv.x)[d], hx = (&hv.x)[d];
#pragma unroll
        for (int j = 0; j < 10; ++j) {
            ssi[j] = fmaf(sx, wsb[d * 10 + j], ssi[j]);
            shh[j] = fmaf(hx, whb[d * 10 + j], shh[j]);
        }
    }
#pragma unroll
    for (int j = 0; j < 10; ++j) {
#pragma unroll
        for (int off = 32; off > 0; off >>= 1) {
            ssi[j] += __shfl_down(ssi[j], off, 64);
            shh[j] += __shfl_down(shh[j], off, 64);
        }
    }
    __shared__ float rs[4][10], rh[4][10];
    if (ln == 0) {
#pragma unroll
        for (int j = 0; j < 10; ++j) { rs[wv][j] = ssi[j]; rh[wv][j] = shh[j]; }
    }
    __syncthreads();

    if (t == 0 && tid < 10)
        siW0out[cb * 10 + tid] = rs[0][tid] + rs[1][tid] + rs[2][tid] + rs[3][tid];

    if (tid == 0) {
        float u10[10];
#pragma unroll
        for (int j = 0; j < 10; ++j)
            u10[j] = rs[0][j] + rs[1][j] + rs[2][j] + rs[3][j] +
                     rh[0][j] + rh[1][j] + rh[2][j] + rh[3][j];
        const float sc = mlp_head(u10, b0, g0, be0, m0, v0,
                                  W1, b1, g1, be1, m1, v1, W2, b2);
        w[t * 64 + cb] = expf(sc);   // |sc| BN-bounded -> no max-sub needed
    }
}

// ---------------------------------------------------------------------------
// kB: FUSED single h-pass. Block (ts,cb): 16 rows h[t=16ts+i, cb, 0:1024],
// each read once (coalesced float4, prefetched one row ahead). Per row:
//   (1) weighted-sum accumulate  wacc += w[t] * hv      (k_wsum pattern)
//   (2) score partial            sacc[j] += hv.d * wf[d][j]
// W0 fragment (40 floats) lives in registers, reused x16 rows. Per-row wave
// shfl-reduce -> lane0 parks 10 floats in LDS; ONE barrier at end; threads
// tid<16 finish cross-wave sum + MLP head -> escore. h is read ONCE total.
// ---------------------------------------------------------------------------
__global__ __launch_bounds__(256) void k_fused(
    const float* __restrict__ h,  const float* __restrict__ W0,
    const float* __restrict__ w,  const float* __restrict__ siW0,
    const float* __restrict__ b0, const float* __restrict__ g0,
    const float* __restrict__ be0,const float* __restrict__ m0,
    const float* __restrict__ v0,
    const float* __restrict__ W1, const float* __restrict__ b1,
    const float* __restrict__ g1, const float* __restrict__ be1,
    const float* __restrict__ m1, const float* __restrict__ v1,
    const float* __restrict__ W2, const float* __restrict__ b2,
    float* __restrict__ escore, float* __restrict__ part) {
    const int cb  = blockIdx.x & 63;
    const int ts  = blockIdx.x >> 6;        // 0..31
    const int tid = threadIdx.x;
    const int wv  = tid >> 6, ln = tid & 63;

    // W0 fragment: rows 1024+4*tid .. +3, all 10 cols = 40 consecutive floats
    float wf[40];
    {
        const float4* wb = (const float4*)(W0 + (size_t)(1024 + 4 * tid) * 10);
#pragma unroll
        for (int q = 0; q < 10; ++q) {
            const float4 v4 = wb[q];
            wf[4 * q + 0] = v4.x; wf[4 * q + 1] = v4.y;
            wf[4 * q + 2] = v4.z; wf[4 * q + 3] = v4.w;
        }
    }

    __shared__ float red[4][16][10];

    const float* hp = h + (size_t)(ts * 16) * C + (size_t)cb * HU + tid * 4;
    const float* wt = w + ts * 16;          // uniform -> s_load

    float4 wacc = {0.f, 0.f, 0.f, 0.f};
    float4 hv = *(const float4*)(hp);       // prefetch row 0

#pragma unroll 4
    for (int i = 0; i < 16; ++i) {
        const float4 hcur = hv;
        if (i + 1 < 16)
            hv = *(const float4*)(hp + (size_t)(i + 1) * C);  // prefetch next

        // (1) weighted sum with the t-th used weight (uniform scalar)
        const float av = wt[i];
        wacc.x = fmaf(av, hcur.x, wacc.x);
        wacc.y = fmaf(av, hcur.y, wacc.y);
        wacc.z = fmaf(av, hcur.z, wacc.z);
        wacc.w = fmaf(av, hcur.w, wacc.w);

        // (2) score partial for (t = 16ts+i, b = cb)
        float sacc[10];
#pragma unroll
        for (int j = 0; j < 10; ++j) sacc[j] = 0.f;
#pragma unroll
        for (int d = 0; d < 4; ++d) {
            const float hx = (&hcur.x)[d];
#pragma unroll
            for (int j = 0; j < 10; ++j)
                sacc[j] = fmaf(hx, wf[d * 10 + j], sacc[j]);
        }
#pragma unroll
        for (int j = 0; j < 10; ++j) {
#pragma unroll
            for (int off = 32; off > 0; off >>= 1)
                sacc[j] += __shfl_down(sacc[j], off, 64);
        }
        if (ln == 0) {
#pragma unroll
            for (int j = 0; j < 10; ++j) red[wv][i][j] = sacc[j];
        }
    }

    // part store first: gets the write in flight under the reduction tail
    *(float4*)(part + (size_t)ts * C + (size_t)cb * HU + tid * 4) = wacc;

    __syncthreads();
    if (tid < 16) {
        float u10[10];
#pragma unroll
        for (int j = 0; j < 10; ++j)
            u10[j] = red[0][tid][j] + red[1][tid][j] + red[2][tid][j] +
                     red[3][tid][j] + siW0[cb * 10 + j];
        const float sc = mlp_head(u10, b0, g0, be0, m0, v0,
                                  W1, b1, g1, be1, m1, v1, W2, b2);
        escore[(ts * 16 + tid) * 64 + cb] = expf(sc);
    }
}

// ---------------------------------------------------------------------------
// kC: Z = sum(escore[0:32768]) (redundant per block, L2-hot), then
// out[c] = (1/Z) * sum_ts part[ts][c].  Grid 64 x 256 threads.
// ---------------------------------------------------------------------------
__global__ __launch_bounds__(256) void k_out(const float* __restrict__ part,
                                             const float* __restrict__ escore,
                                             float* __restrict__ out) {
    const int tid = threadIdx.x;
    const int wv  = tid >> 6, ln = tid & 63;

    float zs = 0.f;
#pragma unroll
    for (int q = 0; q < 32; ++q) {
        const float4 v = ((const float4*)escore)[tid + 256 * q];
        zs += v.x + v.y + v.z + v.w;
    }
#pragma unroll
    for (int off = 32; off > 0; off >>= 1)
        zs += __shfl_down(zs, off, 64);
    __shared__ float zr[4];
    __shared__ float sinv;
    if (ln == 0) zr[wv] = zs;
    __syncthreads();
    if (tid == 0) sinv = 1.0f / (zr[0] + zr[1] + zr[2] + zr[3]);
    __syncthreads();
    const float invZ = sinv;

    const int c = blockIdx.x * 1024 + tid * 4;
    float4 s = {0.f, 0.f, 0.f, 0.f};
#pragma unroll 8
    for (int ts = 0; ts < TSPLIT; ++ts) {
        const float4 v = *(const float4*)(part + (size_t)ts * C + c);
        s.x += v.x; s.y += v.y; s.z += v.z; s.w += v.w;
    }
    s.x *= invZ; s.y *= invZ; s.z *= invZ; s.w *= invZ;
    *(float4*)(out + c) = s;
}

// ---------------------------------------------------------------------------
extern "C" void kernel_launch(void* const* d_in, const int* in_sizes, int n_in,
                              void* d_out, int out_size, void* d_ws, size_t ws_size,
                              hipStream_t stream) {
    const float* si  = (const float*)d_in[0];
    const float* h   = (const float*)d_in[1];
    const float* W0  = (const float*)d_in[2];
    const float* b0  = (const float*)d_in[3];
    const float* g0  = (const float*)d_in[4];
    const float* be0 = (const float*)d_in[5];
    const float* m0  = (const float*)d_in[6];
    const float* v0  = (const float*)d_in[7];
    const float* W1  = (const float*)d_in[8];
    const float* b1  = (const float*)d_in[9];
    const float* g1  = (const float*)d_in[10];
    const float* be1 = (const float*)d_in[11];
    const float* m1  = (const float*)d_in[12];
    const float* v1  = (const float*)d_in[13];
    const float* W2  = (const float*)d_in[14];
    const float* b2  = (const float*)d_in[15];

    float* ws     = (float*)d_ws;
    float* siW0   = ws + OFF_SIW0;
    float* w      = ws + OFF_W;
    float* escore = ws + OFF_ESC;
    float* part   = ws + OFF_PART;
    float* out    = (float*)d_out;

    hipLaunchKernelGGL(k_weights, dim3(512),  dim3(256), 0, stream, h, si, W0,
                       b0, g0, be0, m0, v0, W1, b1, g1, be1, m1, v1, W2, b2,
                       w, siW0);
    hipLaunchKernelGGL(k_fused,   dim3(2048), dim3(256), 0, stream, h, W0, w, siW0,
                       b0, g0, be0, m0, v0, W1, b1, g1, be1, m1, v1, W2, b2,
                       escore, part);
    hipLaunchKernelGGL(k_out,     dim3(64),   dim3(256), 0, stream, part, escore, out);
}

// Round 7
// 272.925 us; speedup vs baseline: 1.0395x; 1.0395x over previous
//
#include <hip/hip_runtime.h>

#define EPS 1e-5f

// Problem dims (fixed by setup_inputs)
constexpr int T  = 512;
constexpr int B  = 64;
constexpr int HU = 1024;
constexpr int S  = 1024;
constexpr int C  = B * HU;       // 65536 (b,hu) columns
constexpr int TCHUNK = 64;       // t rows per mega block
constexpr int NTC = T / TCHUNK;  // 8 part slabs
constexpr int KC  = 128;         // k per LDS tile
constexpr int NCH = HU / KC;     // 8 chunks
constexpr int LDR = KC + 1;      // 129: stride => all LDS phases <=2 lanes/bank

// ws layout (in floats); high-water ~2.3 MB
// r6 audit: all global/LDS accesses bounds-checked; no ws read-before-write;
// no atomics; no host API in kernel_launch. Resubmitted verbatim after infra
// failure (same signature as r2, which ran clean on resubmit in r3).
constexpr size_t OFF_SIW0 = 0;            // [64][10]
constexpr size_t OFF_W    = 1024;         // [512]   e^{s_tau}, tau<512
constexpr size_t OFF_ESC  = 2048;         // [32768] e^{s} for ALL (t,b) -> Z
constexpr size_t OFF_PART = 35840;        // [8][65536] partial weighted sums

// ---------------------------------------------------------------------------
// MLP head (10 -> 5 -> 1)
// ---------------------------------------------------------------------------
__device__ __forceinline__ float mlp_head(
    const float* __restrict__ u10,
    const float* __restrict__ b0, const float* __restrict__ g0,
    const float* __restrict__ be0,const float* __restrict__ m0,
    const float* __restrict__ v0,
    const float* __restrict__ W1, const float* __restrict__ b1,
    const float* __restrict__ g1, const float* __restrict__ be1,
    const float* __restrict__ m1, const float* __restrict__ v1,
    const float* __restrict__ W2, const float* __restrict__ b2) {
    float y[10];
#pragma unroll
    for (int j = 0; j < 10; ++j) {
        float u = (u10[j] + b0[j] - m0[j]) * (1.0f / sqrtf(v0[j] + EPS)) * g0[j]
                  + be0[j];
        y[j] = fmaxf(u, 0.f);
    }
    float z[5];
#pragma unroll
    for (int i = 0; i < 5; ++i) {
        float u = b1[i];
#pragma unroll
        for (int j = 0; j < 10; ++j) u = fmaf(y[j], W1[j * 5 + i], u);
        u = (u - m1[i]) * (1.0f / sqrtf(v1[i] + EPS)) * g1[i] + be1[i];
        z[i] = fmaxf(u, 0.f);
    }
    float sc = b2[0];
#pragma unroll
    for (int i = 0; i < 5; ++i) sc = fmaf(z[i], W2[i], sc);
    return sc;
}

// ---------------------------------------------------------------------------
// kA: the 512 USED weights w[tau] = e^{s(t,b)}, tau = t*64+b, t<8.
// Blocks with t==0 also export siW0[b][10]. (Proven in r5 — unchanged.)
// ---------------------------------------------------------------------------
__global__ __launch_bounds__(256) void k_weights(
    const float* __restrict__ h,  const float* __restrict__ si,
    const float* __restrict__ W0,
    const float* __restrict__ b0, const float* __restrict__ g0,
    const float* __restrict__ be0,const float* __restrict__ m0,
    const float* __restrict__ v0,
    const float* __restrict__ W1, const float* __restrict__ b1,
    const float* __restrict__ g1, const float* __restrict__ be1,
    const float* __restrict__ m1, const float* __restrict__ v1,
    const float* __restrict__ W2, const float* __restrict__ b2,
    float* __restrict__ w, float* __restrict__ siW0out) {
    const int e   = blockIdx.x;
    const int t   = e >> 6;              // 0..7
    const int cb  = e & 63;              // b
    const int tid = threadIdx.x;
    const int wv  = tid >> 6, ln = tid & 63;

    const float4 hv = *(const float4*)(h  + (size_t)t  * C + (size_t)cb * HU + tid * 4);
    const float4 sv = *(const float4*)(si + (size_t)cb * S + tid * 4);
    const float* wsb = W0 + (size_t)(4 * tid) * 10;          // si half rows
    const float* whb = W0 + (size_t)(1024 + 4 * tid) * 10;   // h half rows

    float ssi[10], shh[10];
#pragma unroll
    for (int j = 0; j < 10; ++j) { ssi[j] = 0.f; shh[j] = 0.f; }
#pragma unroll
    for (int d = 0; d < 4; ++d) {
        const float sx = (&sv.x)[d], hx = (&hv.x)[d];
#pragma unroll
        for (int j = 0; j < 10; ++j) {
            ssi[j] = fmaf(sx, wsb[d * 10 + j], ssi[j]);
            shh[j] = fmaf(hx, whb[d * 10 + j], shh[j]);
        }
    }
#pragma unroll
    for (int j = 0; j < 10; ++j) {
#pragma unroll
        for (int off = 32; off > 0; off >>= 1) {
            ssi[j] += __shfl_down(ssi[j], off, 64);
            shh[j] += __shfl_down(shh[j], off, 64);
        }
    }
    __shared__ float rs[4][10], rh[4][10];
    if (ln == 0) {
#pragma unroll
        for (int j = 0; j < 10; ++j) { rs[wv][j] = ssi[j]; rh[wv][j] = shh[j]; }
    }
    __syncthreads();

    if (t == 0 && tid < 10)
        siW0out[cb * 10 + tid] = rs[0][tid] + rs[1][tid] + rs[2][tid] + rs[3][tid];

    if (tid == 0) {
        float u10[10];
#pragma unroll
        for (int j = 0; j < 10; ++j)
            u10[j] = rs[0][j] + rs[1][j] + rs[2][j] + rs[3][j] +
                     rh[0][j] + rh[1][j] + rh[2][j] + rh[3][j];
        const float sc = mlp_head(u10, b0, g0, be0, m0, v0,
                                  W1, b1, g1, be1, m1, v1, W2, b2);
        w[t * 64 + cb] = expf(sc);   // |sc| BN-bounded -> no max-sub needed
    }
}

// ---------------------------------------------------------------------------
// kB "mega": ONE h pass does BOTH scores and weighted sums.
// Block (tc, b): 64 t-rows x 1024 k for one b, via 8 LDS tiles [64][128]
// (stride 129). Per chunk:
//   stage (reg-prefetched float4) -> barrier ->
//   scores: lane ln = t-row, wave wv k-slice [32wv,32wv+32) uniform ->
//           W0 scalar loads, sacc[10] in regs, NO cross-lane ops;
//   colsum: thread pair (kk=tid>>1, half) sums w[t]*tile[t][kk] over 32 rows
//           (conflict-free: bank=(r+kk)%32), one shfl_xor, write part[tc].
// Epilogue: one LDS park + head per t-row -> escore. h read ONCE.
// ---------------------------------------------------------------------------
__global__ __launch_bounds__(256) void k_mega(
    const float* __restrict__ h,  const float* __restrict__ W0,
    const float* __restrict__ w,  const float* __restrict__ siW0,
    const float* __restrict__ b0, const float* __restrict__ g0,
    const float* __restrict__ be0,const float* __restrict__ m0,
    const float* __restrict__ v0,
    const float* __restrict__ W1, const float* __restrict__ b1,
    const float* __restrict__ g1, const float* __restrict__ be1,
    const float* __restrict__ m1, const float* __restrict__ v1,
    const float* __restrict__ W2, const float* __restrict__ b2,
    float* __restrict__ escore, float* __restrict__ part) {
    const int b   = blockIdx.x & 63;
    const int tc  = blockIdx.x >> 6;     // 0..7
    const int tid = threadIdx.x;
    const int wv  = tid >> 6, ln = tid & 63;

    __shared__ float sh[64 * LDR];       // 33 KB tile
    __shared__ float park[4][64][10];    // 10 KB score partials
    __shared__ float wsl[64];            // this block's 64 weights

    if (tid < 64) wsl[tid] = w[tc * 64 + tid];

    const float* hb = h + (size_t)(tc * 64) * C + (size_t)b * HU;
    const int srow = tid >> 5;           // staging: row = 8q + srow
    const int scol = (tid & 31) * 4;     // 32 float4 per row

    // prologue: chunk 0 into registers (8 x float4 per thread)
    float4 stg[8];
#pragma unroll
    for (int q = 0; q < 8; ++q)
        stg[q] = *(const float4*)(hb + (size_t)(8 * q + srow) * C + scol);

    const int klo = __builtin_amdgcn_readfirstlane(32 * wv);
    const int kk  = tid >> 1;            // colsum column 0..127
    const int hlf = tid & 1;             // row half

    float sacc[10];
#pragma unroll
    for (int j = 0; j < 10; ++j) sacc[j] = 0.f;

    for (int c = 0; c < NCH; ++c) {
        if (c > 0) __syncthreads();      // prior chunk's readers done
#pragma unroll
        for (int q = 0; q < 8; ++q) {
            float* dst = sh + (8 * q + srow) * LDR + scol;
            dst[0] = stg[q].x; dst[1] = stg[q].y;
            dst[2] = stg[q].z; dst[3] = stg[q].w;
        }
        if (c + 1 < NCH) {               // issue next chunk early (T14)
#pragma unroll
            for (int q = 0; q < 8; ++q)
                stg[q] = *(const float4*)(hb + (size_t)(8 * q + srow) * C +
                                          (c + 1) * KC + scol);
        }
        __syncthreads();                 // tile ready

        // ---- scores: 32 uniform k's for this wave, lane = t-row ----
        const float* wp  = W0 + (size_t)(1024 + c * KC + klo) * 10;
        const float* shp = sh + ln * LDR + klo;
#pragma unroll
        for (int i = 0; i < 32; ++i) {
            const float hx = shp[i];     // bank (ln+klo+i)%32 -> 2/bank, free
#pragma unroll
            for (int j = 0; j < 10; ++j)
                sacc[j] = fmaf(hx, wp[i * 10 + j], sacc[j]);
        }

        // ---- colsum: part[tc][b][c*128+kk] = sum_t w[t]*tile[t][kk] ----
        float s = 0.f;
        const float* shc = sh + (32 * hlf) * LDR + kk;
        const float* wl  = wsl + 32 * hlf;
#pragma unroll
        for (int r = 0; r < 32; ++r)
            s = fmaf(wl[r], shc[(size_t)r * LDR], s);   // bank (r+kk)%32, free
        s += __shfl_xor(s, 1, 64);       // combine the two row-halves
        if (!hlf)
            part[(size_t)tc * C + (size_t)b * HU + c * KC + kk] = s;
    }

    // ---- epilogue: one park + head per t-row ----
#pragma unroll
    for (int j = 0; j < 10; ++j) park[wv][ln][j] = sacc[j];
    __syncthreads();
    if (tid < 64) {
        float u10[10];
#pragma unroll
        for (int j = 0; j < 10; ++j)
            u10[j] = park[0][tid][j] + park[1][tid][j] + park[2][tid][j] +
                     park[3][tid][j] + siW0[b * 10 + j];
        const float sc = mlp_head(u10, b0, g0, be0, m0, v0,
                                  W1, b1, g1, be1, m1, v1, W2, b2);
        escore[(size_t)(tc * 64 + tid) * 64 + b] = expf(sc);
    }
}

// ---------------------------------------------------------------------------
// kC: Z = sum(escore) (redundant per block, L2-hot), then
// out[c] = (1/Z) * sum_tc part[tc][c].  Grid 64 x 256 threads.
// ---------------------------------------------------------------------------
__global__ __launch_bounds__(256) void k_out(const float* __restrict__ part,
                                             const float* __restrict__ escore,
                                             float* __restrict__ out) {
    const int tid = threadIdx.x;
    const int wv  = tid >> 6, ln = tid & 63;

    float zs = 0.f;
#pragma unroll
    for (int q = 0; q < 32; ++q) {
        const float4 v = ((const float4*)escore)[tid + 256 * q];
        zs += v.x + v.y + v.z + v.w;
    }
#pragma unroll
    for (int off = 32; off > 0; off >>= 1)
        zs += __shfl_down(zs, off, 64);
    __shared__ float zr[4];
    __shared__ float sinv;
    if (ln == 0) zr[wv] = zs;
    __syncthreads();
    if (tid == 0) sinv = 1.0f / (zr[0] + zr[1] + zr[2] + zr[3]);
    __syncthreads();
    const float invZ = sinv;

    const int c = blockIdx.x * 1024 + tid * 4;
    float4 s = {0.f, 0.f, 0.f, 0.f};
#pragma unroll
    for (int ts = 0; ts < NTC; ++ts) {
        const float4 v = *(const float4*)(part + (size_t)ts * C + c);
        s.x += v.x; s.y += v.y; s.z += v.z; s.w += v.w;
    }
    s.x *= invZ; s.y *= invZ; s.z *= invZ; s.w *= invZ;
    *(float4*)(out + c) = s;
}

// ---------------------------------------------------------------------------
extern "C" void kernel_launch(void* const* d_in, const int* in_sizes, int n_in,
                              void* d_out, int out_size, void* d_ws, size_t ws_size,
                              hipStream_t stream) {
    const float* si  = (const float*)d_in[0];
    const float* h   = (const float*)d_in[1];
    const float* W0  = (const float*)d_in[2];
    const float* b0  = (const float*)d_in[3];
    const float* g0  = (const float*)d_in[4];
    const float* be0 = (const float*)d_in[5];
    const float* m0  = (const float*)d_in[6];
    const float* v0  = (const float*)d_in[7];
    const float* W1  = (const float*)d_in[8];
    const float* b1  = (const float*)d_in[9];
    const float* g1  = (const float*)d_in[10];
    const float* be1 = (const float*)d_in[11];
    const float* m1  = (const float*)d_in[12];
    const float* v1  = (const float*)d_in[13];
    const float* W2  = (const float*)d_in[14];
    const float* b2  = (const float*)d_in[15];

    float* ws     = (float*)d_ws;
    float* siW0   = ws + OFF_SIW0;
    float* w      = ws + OFF_W;
    float* escore = ws + OFF_ESC;
    float* part   = ws + OFF_PART;
    float* out    = (float*)d_out;

    hipLaunchKernelGGL(k_weights, dim3(512), dim3(256), 0, stream, h, si, W0,
                       b0, g0, be0, m0, v0, W1, b1, g1, be1, m1, v1, W2, b2,
                       w, siW0);
    hipLaunchKernelGGL(k_mega,    dim3(512), dim3(256), 0, stream, h, W0, w, siW0,
                       b0, g0, be0, m0, v0, W1, b1, g1, be1, m1, v1, W2, b2,
                       escore, part);
    hipLaunchKernelGGL(k_out,     dim3(64),  dim3(256), 0, stream, part, escore, out);
}

// Round 8
// 250.400 us; speedup vs baseline: 1.1330x; 1.0900x over previous
//
#include <hip/hip_runtime.h>

#define EPS 1e-5f

// Problem dims (fixed by setup_inputs)
constexpr int T  = 512;
constexpr int B  = 64;
constexpr int HU = 1024;
constexpr int S  = 1024;
constexpr int C  = B * HU;       // 65536 (b,hu) columns
constexpr int TCHUNK = 64;       // t rows per mega block
constexpr int NTC = T / TCHUNK;  // 8 part slabs
constexpr int KC  = 128;         // k per LDS tile
constexpr int NCH = HU / KC;     // 8 chunks
constexpr int LDR = KC + 1;      // 129 (odd): read banks (ln+k)%32 -> <=2-way

// ws layout (in floats); high-water ~2.3 MB
constexpr size_t OFF_SIW0 = 0;            // [64][10]
constexpr size_t OFF_W    = 1024;         // [512]   e^{s_tau}, tau<512
constexpr size_t OFF_ESC  = 2048;         // [32768] e^{s} for ALL (t,b) -> Z
constexpr size_t OFF_PART = 35840;        // [8][65536] partial weighted sums

// ---------------------------------------------------------------------------
// MLP head (10 -> 5 -> 1)
// ---------------------------------------------------------------------------
__device__ __forceinline__ float mlp_head(
    const float* __restrict__ u10,
    const float* __restrict__ b0, const float* __restrict__ g0,
    const float* __restrict__ be0,const float* __restrict__ m0,
    const float* __restrict__ v0,
    const float* __restrict__ W1, const float* __restrict__ b1,
    const float* __restrict__ g1, const float* __restrict__ be1,
    const float* __restrict__ m1, const float* __restrict__ v1,
    const float* __restrict__ W2, const float* __restrict__ b2) {
    float y[10];
#pragma unroll
    for (int j = 0; j < 10; ++j) {
        float u = (u10[j] + b0[j] - m0[j]) * (1.0f / sqrtf(v0[j] + EPS)) * g0[j]
                  + be0[j];
        y[j] = fmaxf(u, 0.f);
    }
    float z[5];
#pragma unroll
    for (int i = 0; i < 5; ++i) {
        float u = b1[i];
#pragma unroll
        for (int j = 0; j < 10; ++j) u = fmaf(y[j], W1[j * 5 + i], u);
        u = (u - m1[i]) * (1.0f / sqrtf(v1[i] + EPS)) * g1[i] + be1[i];
        z[i] = fmaxf(u, 0.f);
    }
    float sc = b2[0];
#pragma unroll
    for (int i = 0; i < 5; ++i) sc = fmaf(z[i], W2[i], sc);
    return sc;
}

// ---------------------------------------------------------------------------
// kA: the 512 USED weights w[tau] = e^{s(t,b)}, tau = t*64+b, t<8.
// Blocks with t==0 also export siW0[b][10]. (Proven in r5/r7 — unchanged.)
// ---------------------------------------------------------------------------
__global__ __launch_bounds__(256) void k_weights(
    const float* __restrict__ h,  const float* __restrict__ si,
    const float* __restrict__ W0,
    const float* __restrict__ b0, const float* __restrict__ g0,
    const float* __restrict__ be0,const float* __restrict__ m0,
    const float* __restrict__ v0,
    const float* __restrict__ W1, const float* __restrict__ b1,
    const float* __restrict__ g1, const float* __restrict__ be1,
    const float* __restrict__ m1, const float* __restrict__ v1,
    const float* __restrict__ W2, const float* __restrict__ b2,
    float* __restrict__ w, float* __restrict__ siW0out) {
    const int e   = blockIdx.x;
    const int t   = e >> 6;              // 0..7
    const int cb  = e & 63;              // b
    const int tid = threadIdx.x;
    const int wv  = tid >> 6, ln = tid & 63;

    const float4 hv = *(const float4*)(h  + (size_t)t  * C + (size_t)cb * HU + tid * 4);
    const float4 sv = *(const float4*)(si + (size_t)cb * S + tid * 4);
    const float* wsb = W0 + (size_t)(4 * tid) * 10;          // si half rows
    const float* whb = W0 + (size_t)(1024 + 4 * tid) * 10;   // h half rows

    float ssi[10], shh[10];
#pragma unroll
    for (int j = 0; j < 10; ++j) { ssi[j] = 0.f; shh[j] = 0.f; }
#pragma unroll
    for (int d = 0; d < 4; ++d) {
        const float sx = (&sv.x)[d], hx = (&hv.x)[d];
#pragma unroll
        for (int j = 0; j < 10; ++j) {
            ssi[j] = fmaf(sx, wsb[d * 10 + j], ssi[j]);
            shh[j] = fmaf(hx, whb[d * 10 + j], shh[j]);
        }
    }
#pragma unroll
    for (int j = 0; j < 10; ++j) {
#pragma unroll
        for (int off = 32; off > 0; off >>= 1) {
            ssi[j] += __shfl_down(ssi[j], off, 64);
            shh[j] += __shfl_down(shh[j], off, 64);
        }
    }
    __shared__ float rs[4][10], rh[4][10];
    if (ln == 0) {
#pragma unroll
        for (int j = 0; j < 10; ++j) { rs[wv][j] = ssi[j]; rh[wv][j] = shh[j]; }
    }
    __syncthreads();

    if (t == 0 && tid < 10)
        siW0out[cb * 10 + tid] = rs[0][tid] + rs[1][tid] + rs[2][tid] + rs[3][tid];

    if (tid == 0) {
        float u10[10];
#pragma unroll
        for (int j = 0; j < 10; ++j)
            u10[j] = rs[0][j] + rs[1][j] + rs[2][j] + rs[3][j] +
                     rh[0][j] + rh[1][j] + rh[2][j] + rh[3][j];
        const float sc = mlp_head(u10, b0, g0, be0, m0, v0,
                                  W1, b1, g1, be1, m1, v1, W2, b2);
        w[t * 64 + cb] = expf(sc);   // |sc| BN-bounded -> no max-sub needed
    }
}

// ---------------------------------------------------------------------------
// kB "mega" v2: ONE h pass for BOTH scores and weighted sums.
// 512 threads (8 waves) -> 16 waves/CU occupancy (2 blocks/CU, 53.8 KB LDS).
// Staging is b32 at stride-32 cols: thread owns (row=16q+tid>>5, col=32d+tid&31)
//   -> LDS write banks (row+lane)%32 all-distinct (conflict-free; fixes r7's
//      4.19M conflicts from misaligned float4 writes at odd stride), and
//   -> global b32 loads are 128B-segment coalesced per half-wave.
// Per chunk: barrier; write stg->LDS; issue next chunk's 16 loads (T14);
// barrier; scores (lane=t-row, wave k-slice 16 uniform k -> W0 scalar loads);
// colsum (thread (kk,qtr): 16 rows, banks (r+kk)%32, 2x shfl_xor, store).
// Epilogue: park 8x64x10 + per-t-row head -> escore. h read ONCE.
// ---------------------------------------------------------------------------
__global__ __launch_bounds__(512) void k_mega(
    const float* __restrict__ h,  const float* __restrict__ W0,
    const float* __restrict__ w,  const float* __restrict__ siW0,
    const float* __restrict__ b0, const float* __restrict__ g0,
    const float* __restrict__ be0,const float* __restrict__ m0,
    const float* __restrict__ v0,
    const float* __restrict__ W1, const float* __restrict__ b1,
    const float* __restrict__ g1, const float* __restrict__ be1,
    const float* __restrict__ m1, const float* __restrict__ v1,
    const float* __restrict__ W2, const float* __restrict__ b2,
    float* __restrict__ escore, float* __restrict__ part) {
    const int b   = blockIdx.x & 63;
    const int tc  = blockIdx.x >> 6;     // 0..7
    const int tid = threadIdx.x;
    const int wv  = tid >> 6;            // 0..7
    const int ln  = tid & 63;

    __shared__ float sh[64 * LDR];       // 33.0 KB tile
    __shared__ float park[8][64][10];    // 20.5 KB score partials
    __shared__ float wsl[64];            // this block's 64 weights

    if (tid < 64) wsl[tid] = w[tc * 64 + tid];

    const float* hb = h + (size_t)(tc * 64) * C + (size_t)b * HU;
    const int srow  = tid >> 5;          // 0..15 : row = 16q + srow
    const int slane = tid & 31;          // col   = 32d + slane

    // prologue: chunk 0, 16 b32 per thread (coalesced 128B segments)
    float stg[16];
#pragma unroll
    for (int q = 0; q < 4; ++q)
#pragma unroll
        for (int d = 0; d < 4; ++d)
            stg[4 * q + d] = hb[(size_t)(16 * q + srow) * C + 32 * d + slane];

    const int klo = __builtin_amdgcn_readfirstlane(16 * wv);  // wave k-slice
    const int kk  = tid >> 2;            // colsum column 0..127
    const int qtr = tid & 3;             // 16-row quarter

    float sacc[10];
#pragma unroll
    for (int j = 0; j < 10; ++j) sacc[j] = 0.f;

    for (int c = 0; c < NCH; ++c) {
        if (c > 0) __syncthreads();      // prior chunk's readers done
        // conflict-free b32 writes: bank (row + slane)%32, lanes all-distinct
#pragma unroll
        for (int q = 0; q < 4; ++q)
#pragma unroll
            for (int d = 0; d < 4; ++d)
                sh[(16 * q + srow) * LDR + 32 * d + slane] = stg[4 * q + d];
        if (c + 1 < NCH) {               // issue next chunk early (T14)
#pragma unroll
            for (int q = 0; q < 4; ++q)
#pragma unroll
                for (int d = 0; d < 4; ++d)
                    stg[4 * q + d] = hb[(size_t)(16 * q + srow) * C +
                                        (c + 1) * KC + 32 * d + slane];
        }
        __syncthreads();                 // tile ready

        // ---- scores: 16 uniform k's for this wave, lane = t-row ----
        const float* wp  = W0 + (size_t)(1024 + c * KC + klo) * 10;
        const float* shp = sh + ln * LDR + klo;
#pragma unroll
        for (int i = 0; i < 16; ++i) {
            const float hx = shp[i];     // bank (ln+klo+i)%32 -> 2/bank, free
#pragma unroll
            for (int j = 0; j < 10; ++j)
                sacc[j] = fmaf(hx, wp[i * 10 + j], sacc[j]);
        }

        // ---- colsum: part[tc][b][c*128+kk] = sum_t w[t]*tile[t][kk] ----
        float s = 0.f;
        const float* shc = sh + (16 * qtr) * LDR + kk;
        const float* wl  = wsl + 16 * qtr;
#pragma unroll
        for (int r = 0; r < 16; ++r)
            s = fmaf(wl[r], shc[r * LDR], s);   // bank (r+kk)%32, <=2-way
        s += __shfl_xor(s, 1, 64);       // combine quarters
        s += __shfl_xor(s, 2, 64);
        if (qtr == 0)
            part[(size_t)tc * C + (size_t)b * HU + c * KC + kk] = s;
    }

    // ---- epilogue: one park + head per t-row ----
#pragma unroll
    for (int j = 0; j < 10; ++j) park[wv][ln][j] = sacc[j];
    __syncthreads();
    if (tid < 64) {
        float u10[10];
#pragma unroll
        for (int j = 0; j < 10; ++j)
            u10[j] = park[0][tid][j] + park[1][tid][j] + park[2][tid][j] +
                     park[3][tid][j] + park[4][tid][j] + park[5][tid][j] +
                     park[6][tid][j] + park[7][tid][j] + siW0[b * 10 + j];
        const float sc = mlp_head(u10, b0, g0, be0, m0, v0,
                                  W1, b1, g1, be1, m1, v1, W2, b2);
        escore[(size_t)(tc * 64 + tid) * 64 + b] = expf(sc);
    }
}

// ---------------------------------------------------------------------------
// kC: Z = sum(escore) (redundant per block, L2-hot), then
// out[c] = (1/Z) * sum_tc part[tc][c].  Grid 64 x 256 threads.
// ---------------------------------------------------------------------------
__global__ __launch_bounds__(256) void k_out(const float* __restrict__ part,
                                             const float* __restrict__ escore,
                                             float* __restrict__ out) {
    const int tid = threadIdx.x;
    const int wv  = tid >> 6, ln = tid & 63;

    float zs = 0.f;
#pragma unroll
    for (int q = 0; q < 32; ++q) {
        const float4 v = ((const float4*)escore)[tid + 256 * q];
        zs += v.x + v.y + v.z + v.w;
    }
#pragma unroll
    for (int off = 32; off > 0; off >>= 1)
        zs += __shfl_down(zs, off, 64);
    __shared__ float zr[4];
    __shared__ float sinv;
    if (ln == 0) zr[wv] = zs;
    __syncthreads();
    if (tid == 0) sinv = 1.0f / (zr[0] + zr[1] + zr[2] + zr[3]);
    __syncthreads();
    const float invZ = sinv;

    const int c = blockIdx.x * 1024 + tid * 4;
    float4 s = {0.f, 0.f, 0.f, 0.f};
#pragma unroll
    for (int ts = 0; ts < NTC; ++ts) {
        const float4 v = *(const float4*)(part + (size_t)ts * C + c);
        s.x += v.x; s.y += v.y; s.z += v.z; s.w += v.w;
    }
    s.x *= invZ; s.y *= invZ; s.z *= invZ; s.w *= invZ;
    *(float4*)(out + c) = s;
}

// ---------------------------------------------------------------------------
extern "C" void kernel_launch(void* const* d_in, const int* in_sizes, int n_in,
                              void* d_out, int out_size, void* d_ws, size_t ws_size,
                              hipStream_t stream) {
    const float* si  = (const float*)d_in[0];
    const float* h   = (const float*)d_in[1];
    const float* W0  = (const float*)d_in[2];
    const float* b0  = (const float*)d_in[3];
    const float* g0  = (const float*)d_in[4];
    const float* be0 = (const float*)d_in[5];
    const float* m0  = (const float*)d_in[6];
    const float* v0  = (const float*)d_in[7];
    const float* W1  = (const float*)d_in[8];
    const float* b1  = (const float*)d_in[9];
    const float* g1  = (const float*)d_in[10];
    const float* be1 = (const float*)d_in[11];
    const float* m1  = (const float*)d_in[12];
    const float* v1  = (const float*)d_in[13];
    const float* W2  = (const float*)d_in[14];
    const float* b2  = (const float*)d_in[15];

    float* ws     = (float*)d_ws;
    float* siW0   = ws + OFF_SIW0;
    float* w      = ws + OFF_W;
    float* escore = ws + OFF_ESC;
    float* part   = ws + OFF_PART;
    float* out    = (float*)d_out;

    hipLaunchKernelGGL(k_weights, dim3(512), dim3(256), 0, stream, h, si, W0,
                       b0, g0, be0, m0, v0, W1, b1, g1, be1, m1, v1, W2, b2,
                       w, siW0);
    hipLaunchKernelGGL(k_mega,    dim3(512), dim3(512), 0, stream, h, W0, w, siW0,
                       b0, g0, be0, m0, v0, W1, b1, g1, be1, m1, v1, W2, b2,
                       escore, part);
    hipLaunchKernelGGL(k_out,     dim3(64),  dim3(256), 0, stream, part, escore, out);
}